// Round 5
// baseline (1176.544 us; speedup 1.0000x reference)
//
#include <hip/hip_runtime.h>
#include <hip/hip_bf16.h>
#include <cstdint>
#include <cstddef>

// Problem constants
#define E_   8
#define H_   2048
#define I_   2816
#define T_   512
#define NPAIR 1024         // T*K (token,k) pairs

// GEMM tiling: no-LDS, no-barrier design. Each wave = independent stream.
#define TM   192           // one m-tile per expert w.h.p. -> weights streamed once
#define TN   16            // 16-col B strip per block -> many blocks, scale uniform
#define BK   64
#define MT_  3             // m-frags per wave (192 / 4 waves / 16)

typedef __attribute__((ext_vector_type(8))) short          bf16x8;
typedef __attribute__((ext_vector_type(4))) float          f32x4;
typedef __attribute__((ext_vector_type(8))) unsigned short u16x8;

__device__ __forceinline__ unsigned short f2bf(float f){
  union { float f; unsigned u; } a; a.f = f;
  unsigned u = a.u;
  unsigned r = u + 0x7fffu + ((u >> 16) & 1u);   // RNE
  return (unsigned short)(r >> 16);
}

__device__ __forceinline__ void cvt4(u16x8& dst, int base, const float4 v, float s){
  __hip_bfloat162 p0 = __float22bfloat162_rn(float2{v.x*s, v.y*s});
  __hip_bfloat162 p1 = __float22bfloat162_rn(float2{v.z*s, v.w*s});
  union { __hip_bfloat162 b; unsigned u; } a0{p0}, a1{p1};
  dst[base+0] = (unsigned short)(a0.u & 0xffff);
  dst[base+1] = (unsigned short)(a0.u >> 16);
  dst[base+2] = (unsigned short)(a1.u & 0xffff);
  dst[base+3] = (unsigned short)(a1.u >> 16);
}

__device__ __forceinline__ bf16x8 cvt8(const float4 a, const float4 b, float s){
  u16x8 r;
  cvt4(r, 0, a, s);
  cvt4(r, 4, b, s);
  union { u16x8 u; bf16x8 h; } c; c.u = r;
  return c.h;
}

// ---------------------------------------------------------------------------
// Routing: bucket 1024 (t,k) pairs by expert; also inverse map slot-of-pair.
// ---------------------------------------------------------------------------
__global__ void route_kernel(const int* __restrict__ ids,
                             int* __restrict__ offs, int* __restrict__ ptok,
                             int* __restrict__ sop){
  __shared__ int scnt[E_];
  __shared__ int scur[E_];
  const int tid = threadIdx.x;
  if (tid < E_) scnt[tid] = 0;
  __syncthreads();
  const int e = ids[tid];
  atomicAdd(&scnt[e], 1);
  __syncthreads();
  if (tid == 0){
    int s = 0;
    for (int i = 0; i < E_; i++){ offs[i] = s; scur[i] = s; s += scnt[i]; }
    offs[E_] = s;
  }
  __syncthreads();
  const int pos = atomicAdd(&scur[e], 1);
  ptok[pos] = tid >> 1;
  sop[tid]  = pos;
}

// ---------------------------------------------------------------------------
// Prep: gather+convert x rows into slot order, bf16. xg[slot][H]
// ---------------------------------------------------------------------------
__global__ void prep_kernel(const float* __restrict__ x, const int* __restrict__ ptok,
                            unsigned short* __restrict__ xg){
  const int slot = blockIdx.x;
  const int tok  = ptok[slot];
  const int k0   = threadIdx.x * 8;
  const float4 v0 = *(const float4*)(x + (size_t)tok*H_ + k0);
  const float4 v1 = *(const float4*)(x + (size_t)tok*H_ + k0 + 4);
  u16x8 o;
  cvt4(o, 0, v0, 1.f);
  cvt4(o, 4, v1, 1.f);
  *(u16x8*)(xg + (size_t)slot*H_ + k0) = o;
}

// ---------------------------------------------------------------------------
// GEMM1: act[slot,i] = silu(x@Wg^T)*(x@Wu^T). No LDS, no barriers: every
// wave streams its B fragments straight from global (fp32 -> xscale -> bf16
// in regs); A fragments from xg (bf16, L2-hot). Latency hidden by wave
// count (16 waves/CU), not intra-wave pipelining.
// grid: (I/TN=176, 6, E=8), block 256.
// ---------------------------------------------------------------------------
__global__ __launch_bounds__(256, 4)
void gemm1_kernel(const unsigned short* __restrict__ xg, const float* __restrict__ w13,
                  const float* __restrict__ s13, const int* __restrict__ offs,
                  unsigned short* __restrict__ act)
{
  const int e   = blockIdx.z;
  const int off = offs[e];
  const int cnt = offs[e+1] - off;
  const int m0  = blockIdx.y * TM;
  if (m0 >= cnt) return;
  const int rows = min(TM, cnt - m0);
  const int nb   = blockIdx.x * TN;

  const int tid  = threadIdx.x;
  const int wave = tid >> 6;
  const int lane = tid & 63;
  const int quad = lane >> 4;
  const int l16  = lane & 15;

  const float* w13e = w13 + (size_t)e * (2*I_) * H_;
  const float* s13e = s13 + (size_t)e * (2*I_/128) * (H_/128);

  // Per-lane B row pointers (gate, up); lane reads row nb+l16, k-offset quad*8
  const float* bP[2];
  bP[0] = w13e + (size_t)(nb + l16) * H_ + quad*8;
  bP[1] = w13e + (size_t)(I_ + nb + l16) * H_ + quad*8;
  const int sbase0 = (nb >> 7) * (H_/128);
  const int sbase1 = (I_/128 + (nb >> 7)) * (H_/128);

  // A fragment row pointers (clamped; OOB rows discarded in epilogue)
  const unsigned short* aP[MT_];
  #pragma unroll
  for (int mt = 0; mt < MT_; mt++){
    int sl = off + m0 + wave*(TM/4) + mt*16 + l16;
    sl = min(sl, NPAIR - 1);
    aP[mt] = xg + (size_t)sl * H_ + quad*8;
  }

  f32x4 acc[2][MT_];
  #pragma unroll
  for (int h = 0; h < 2; h++)
    #pragma unroll
    for (int mt = 0; mt < MT_; mt++)
      acc[h][mt] = (f32x4){0.f, 0.f, 0.f, 0.f};

  for (int kb = 0; kb < H_; kb += BK){
    // issue all loads for this K-tile
    bf16x8 a[2][MT_];
    #pragma unroll
    for (int kk = 0; kk < 2; kk++)
      #pragma unroll
      for (int mt = 0; mt < MT_; mt++)
        a[kk][mt] = *(const bf16x8*)(aP[mt] + kb + kk*32);

    float4 b[2][2][2];   // [hh][kk][half]
    #pragma unroll
    for (int hh = 0; hh < 2; hh++)
      #pragma unroll
      for (int kk = 0; kk < 2; kk++)
        #pragma unroll
        for (int hf = 0; hf < 2; hf++)
          b[hh][kk][hf] = *(const float4*)(bP[hh] + kb + kk*32 + hf*4);

    const float s0 = s13e[sbase0 + (kb >> 7)];
    const float s1 = s13e[sbase1 + (kb >> 7)];

    #pragma unroll
    for (int kk = 0; kk < 2; kk++){
      bf16x8 bv0 = cvt8(b[0][kk][0], b[0][kk][1], s0);
      #pragma unroll
      for (int mt = 0; mt < MT_; mt++)
        acc[0][mt] = __builtin_amdgcn_mfma_f32_16x16x32_bf16(a[kk][mt], bv0, acc[0][mt], 0, 0, 0);
      bf16x8 bv1 = cvt8(b[1][kk][0], b[1][kk][1], s1);
      #pragma unroll
      for (int mt = 0; mt < MT_; mt++)
        acc[1][mt] = __builtin_amdgcn_mfma_f32_16x16x32_bf16(a[kk][mt], bv1, acc[1][mt], 0, 0, 0);
    }
  }

  // epilogue: act = silu(gate)*up  (C layout: col = l16, row = quad*4+r)
  #pragma unroll
  for (int mt = 0; mt < MT_; mt++){
    #pragma unroll
    for (int r = 0; r < 4; r++){
      const int m = wave*(TM/4) + mt*16 + quad*4 + r;
      if (m < rows){
        const float g = acc[0][mt][r];
        const float u = acc[1][mt][r];
        const float sg = g / (1.f + __expf(-g));
        act[(size_t)(off + m0 + m)*I_ + (nb + l16)] = f2bf(sg * u);
      }
    }
  }
}

// ---------------------------------------------------------------------------
// GEMM2: buf[slot,h] = act @ W2^T (unscaled by router weight). Same design.
// grid: (H/TN=128, 6, E=8), block 256.
// ---------------------------------------------------------------------------
__global__ __launch_bounds__(256, 4)
void gemm2_kernel(const unsigned short* __restrict__ act, const float* __restrict__ w2,
                  const float* __restrict__ s2, const int* __restrict__ offs,
                  float* __restrict__ buf)
{
  const int e   = blockIdx.z;
  const int off = offs[e];
  const int cnt = offs[e+1] - off;
  const int m0  = blockIdx.y * TM;
  if (m0 >= cnt) return;
  const int rows = min(TM, cnt - m0);
  const int nb   = blockIdx.x * TN;

  const int tid  = threadIdx.x;
  const int wave = tid >> 6;
  const int lane = tid & 63;
  const int quad = lane >> 4;
  const int l16  = lane & 15;

  const float* w2e = w2 + (size_t)e * H_ * I_;
  const float* s2e = s2 + (size_t)e * (H_/128) * (I_/128);

  const float* bP = w2e + (size_t)(nb + l16) * I_ + quad*8;
  const int sbase = (nb >> 7) * (I_/128);

  const unsigned short* aP[MT_];
  #pragma unroll
  for (int mt = 0; mt < MT_; mt++){
    int sl = off + m0 + wave*(TM/4) + mt*16 + l16;
    sl = min(sl, NPAIR - 1);
    aP[mt] = act + (size_t)sl * I_ + quad*8;
  }

  f32x4 acc[MT_];
  #pragma unroll
  for (int mt = 0; mt < MT_; mt++)
    acc[mt] = (f32x4){0.f, 0.f, 0.f, 0.f};

  for (int kb = 0; kb < I_; kb += BK){
    bf16x8 a[2][MT_];
    #pragma unroll
    for (int kk = 0; kk < 2; kk++)
      #pragma unroll
      for (int mt = 0; mt < MT_; mt++)
        a[kk][mt] = *(const bf16x8*)(aP[mt] + kb + kk*32);

    float4 b[2][2];   // [kk][half]
    #pragma unroll
    for (int kk = 0; kk < 2; kk++)
      #pragma unroll
      for (int hf = 0; hf < 2; hf++)
        b[kk][hf] = *(const float4*)(bP + kb + kk*32 + hf*4);

    const float s = s2e[sbase + (kb >> 7)];

    #pragma unroll
    for (int kk = 0; kk < 2; kk++){
      bf16x8 bv = cvt8(b[kk][0], b[kk][1], s);
      #pragma unroll
      for (int mt = 0; mt < MT_; mt++)
        acc[mt] = __builtin_amdgcn_mfma_f32_16x16x32_bf16(a[kk][mt], bv, acc[mt], 0, 0, 0);
    }
  }

  // epilogue: plain stores per slot row
  #pragma unroll
  for (int mt = 0; mt < MT_; mt++){
    #pragma unroll
    for (int r = 0; r < 4; r++){
      const int m = wave*(TM/4) + mt*16 + quad*4 + r;
      if (m < rows)
        buf[(size_t)(off + m0 + m)*H_ + (nb + l16)] = acc[mt][r];
    }
  }
}

// ---------------------------------------------------------------------------
// Combine: out[t,:] = tw[2t]*buf[sop[2t],:] + tw[2t+1]*buf[sop[2t+1],:]
// ---------------------------------------------------------------------------
__global__ void combine_kernel(const float* __restrict__ buf, const int* __restrict__ sop,
                               const float* __restrict__ tw, float* __restrict__ out){
  const int gid = blockIdx.x*256 + threadIdx.x;
  const int t = gid >> 9;
  const int c = gid & 511;
  const int s0 = sop[2*t], s1 = sop[2*t+1];
  const float w0 = tw[2*t], w1 = tw[2*t+1];
  const float4 v0 = ((const float4*)buf)[(size_t)s0*(H_/4) + c];
  const float4 v1 = ((const float4*)buf)[(size_t)s1*(H_/4) + c];
  float4 o;
  o.x = w0*v0.x + w1*v1.x;
  o.y = w0*v0.y + w1*v1.y;
  o.z = w0*v0.z + w1*v1.z;
  o.w = w0*v0.w + w1*v1.w;
  ((float4*)out)[gid] = o;
}

// ---------------------------------------------------------------------------
extern "C" void kernel_launch(void* const* d_in, const int* in_sizes, int n_in,
                              void* d_out, int out_size, void* d_ws, size_t ws_size,
                              hipStream_t stream){
  const float* x   = (const float*)d_in[0];
  const int*   ids = (const int*)  d_in[1];
  const float* tw  = (const float*)d_in[2];
  const float* w13 = (const float*)d_in[3];
  const float* s13 = (const float*)d_in[4];
  const float* w2  = (const float*)d_in[5];
  const float* s2  = (const float*)d_in[6];
  float* out = (float*)d_out;

  char* ws = (char*)d_ws;
  int* offs = (int*)ws;                                   // 9 ints
  int* ptok = (int*)(ws + 64);                            // 1024 ints
  int* sop  = (int*)(ws + 64 + 4096);                     // 1024 ints
  unsigned short* xg  = (unsigned short*)(ws + 16384);    // [1024][H] bf16 (aliased by buf)
  float*          buf = (float*)(ws + 16384);             // [1024][H] f32
  unsigned short* act = (unsigned short*)(ws + 16384 + (size_t)NPAIR*H_*4);  // [1024][I] bf16

  route_kernel  <<<1, NPAIR, 0, stream>>>(ids, offs, ptok, sop);
  prep_kernel   <<<NPAIR, 256, 0, stream>>>(x, ptok, xg);
  gemm1_kernel  <<<dim3(I_/TN, (NPAIR + TM - 1)/TM, E_), 256, 0, stream>>>(xg, w13, s13, offs, act);
  gemm2_kernel  <<<dim3(H_/TN, (NPAIR + TM - 1)/TM, E_), 256, 0, stream>>>(act, w2, s2, offs, buf);
  combine_kernel<<<(T_*H_/4)/256, 256, 0, stream>>>(buf, sop, tw, out);
}

// Round 6
// 792.396 us; speedup vs baseline: 1.4848x; 1.4848x over previous
//
#include <hip/hip_runtime.h>
#include <hip/hip_bf16.h>
#include <cstdint>
#include <cstddef>

// Problem constants
#define E_   8
#define H_   2048
#define I_   2816
#define T_   512
#define NPAIR 1024         // T*K (token,k) pairs

// GEMM tiling
#define TM   192           // full m coverage per expert -> weights streamed once
#define TN   16            // narrow n-strip -> many independent block-convoys
#define BK   64
#define LDSB 72            // padded LDS row stride (bf16): 144 B, conflict-free frag reads
#define MT_  3             // m-frags per wave (192 / 4 waves / 16)

typedef __attribute__((ext_vector_type(8))) short          bf16x8;
typedef __attribute__((ext_vector_type(4))) float          f32x4;
typedef __attribute__((ext_vector_type(4))) unsigned short u16x4;
typedef __attribute__((ext_vector_type(8))) unsigned short u16x8;

__device__ __forceinline__ unsigned short f2bf(float f){
  union { float f; unsigned u; } a; a.f = f;
  unsigned u = a.u;
  unsigned r = u + 0x7fffu + ((u >> 16) & 1u);   // RNE
  return (unsigned short)(r >> 16);
}

__device__ __forceinline__ void cvt4(unsigned short* dst, const float4 v, float s){
  __hip_bfloat162 p0 = __float22bfloat162_rn(float2{v.x*s, v.y*s});
  __hip_bfloat162 p1 = __float22bfloat162_rn(float2{v.z*s, v.w*s});
  union { __hip_bfloat162 b; unsigned u; } a0{p0}, a1{p1};
  dst[0] = (unsigned short)(a0.u & 0xffff);
  dst[1] = (unsigned short)(a0.u >> 16);
  dst[2] = (unsigned short)(a1.u & 0xffff);
  dst[3] = (unsigned short)(a1.u >> 16);
}

// LDS-only barrier: drain LDS ops, keep global loads in flight across it.
__device__ __forceinline__ void sync_lds(){
  asm volatile("s_waitcnt lgkmcnt(0)\n\ts_barrier" ::: "memory");
}

// ---------------------------------------------------------------------------
// Routing
// ---------------------------------------------------------------------------
__global__ void route_kernel(const int* __restrict__ ids,
                             int* __restrict__ offs, int* __restrict__ ptok,
                             int* __restrict__ sop){
  __shared__ int scnt[E_];
  __shared__ int scur[E_];
  const int tid = threadIdx.x;
  if (tid < E_) scnt[tid] = 0;
  __syncthreads();
  const int e = ids[tid];
  atomicAdd(&scnt[e], 1);
  __syncthreads();
  if (tid == 0){
    int s = 0;
    for (int i = 0; i < E_; i++){ offs[i] = s; scur[i] = s; s += scnt[i]; }
    offs[E_] = s;
  }
  __syncthreads();
  const int pos = atomicAdd(&scur[e], 1);
  ptok[pos] = tid >> 1;
  sop[tid]  = pos;
}

// ---------------------------------------------------------------------------
// Prep: gather+convert x rows into slot order, bf16. xg[slot][H]
// ---------------------------------------------------------------------------
__global__ void prep_kernel(const float* __restrict__ x, const int* __restrict__ ptok,
                            unsigned short* __restrict__ xg){
  const int slot = blockIdx.x;
  const int tok  = ptok[slot];
  const int k0   = threadIdx.x * 8;
  const float4 v0 = *(const float4*)(x + (size_t)tok*H_ + k0);
  const float4 v1 = *(const float4*)(x + (size_t)tok*H_ + k0 + 4);
  u16x8 o;
  cvt4((unsigned short*)&o,     v0, 1.f);
  cvt4((unsigned short*)&o + 4, v1, 1.f);
  *(u16x8*)(xg + (size_t)slot*H_ + k0) = o;
}

// ---------------------------------------------------------------------------
// GEMM1: act[slot,i] = silu(x@Wg^T)*(x@Wu^T). TN=16 n-strip (gate+up = 32 B
// rows). B: coalesced fp32 load -> dist-2 reg prefetch -> dequant cvt -> LDS
// double buffer; lgkmcnt-only barrier. A: frags direct from xg (L2-hot),
// dist-1. grid: (I/TN=176, 6, E=8), block 256.
// ---------------------------------------------------------------------------
__global__ __launch_bounds__(256, 4)
void gemm1_kernel(const unsigned short* __restrict__ xg, const float* __restrict__ w13,
                  const float* __restrict__ s13, const int* __restrict__ offs,
                  unsigned short* __restrict__ act)
{
  const int e   = blockIdx.z;
  const int off = offs[e];
  const int cnt = offs[e+1] - off;
  const int m0  = blockIdx.y * TM;
  if (m0 >= cnt) return;
  const int rows = min(TM, cnt - m0);
  const int nb   = blockIdx.x * TN;

  __shared__ __align__(16) unsigned short Bs[2][2*TN][LDSB];  // 9216 B

  const int tid  = threadIdx.x;
  const int wave = tid >> 6;
  const int lane = tid & 63;
  const int quad = lane >> 4;
  const int l16  = lane & 15;

  const float* w13e = w13 + (size_t)e * (2*I_) * H_;
  const float* s13e = s13 + (size_t)e * (2*I_/128) * (H_/128);

  // B staging map: row = tid>>3 (0..31: gate 0..15, up 16..31), 8 floats/thread
  const int brow = tid >> 3;
  const int bfg  = tid & 7;               // float group: cols bfg*8 .. +7
  const int grow = (brow < TN) ? (nb + brow) : (I_ + nb + (brow - TN));
  const float* bp = w13e + (size_t)grow * H_ + bfg*8;
  const float* sp = s13e + (((brow < TN) ? 0 : (I_/128)) + (nb >> 7)) * (H_/128);

  // A fragment row pointers (clamped; OOB rows discarded in epilogue)
  const unsigned short* aP[MT_];
  #pragma unroll
  for (int mt = 0; mt < MT_; mt++){
    int sl = off + m0 + wave*(TM/4) + mt*16 + l16;
    sl = min(sl, NPAIR - 1);
    aP[mt] = xg + (size_t)sl * H_ + quad*8;
  }

  f32x4 acc[2][MT_];
  #pragma unroll
  for (int h = 0; h < 2; h++)
    #pragma unroll
    for (int mt = 0; mt < MT_; mt++)
      acc[h][mt] = (f32x4){0.f, 0.f, 0.f, 0.f};

  float4 R0[2], R1[2];
  bf16x8 A0[2][MT_], A1[2][MT_];
  float  sE, sO;

  auto loadB = [&](int t, float4* R){
    const float* p = bp + t*BK;
    R[0] = *(const float4*)(p);
    R[1] = *(const float4*)(p + 4);
  };
  auto loadA = [&](int t, bf16x8 (*A)[MT_]){
    #pragma unroll
    for (int kk = 0; kk < 2; kk++)
      #pragma unroll
      for (int mt = 0; mt < MT_; mt++)
        A[kk][mt] = *(const bf16x8*)(aP[mt] + t*BK + kk*32);
  };
  auto storeB = [&](const float4* R, float s, int buf){
    u16x8 w;
    cvt4((unsigned short*)&w,     R[0], s);
    cvt4((unsigned short*)&w + 4, R[1], s);
    *(u16x8*)&Bs[buf][brow][bfg*8] = w;
  };
  auto mfma = [&](int buf, bf16x8 (*A)[MT_]){
    #pragma unroll
    for (int kk = 0; kk < 2; kk++)
      #pragma unroll
      for (int hh = 0; hh < 2; hh++){
        bf16x8 bv = *(const bf16x8*)&Bs[buf][hh*TN + l16][kk*32 + quad*8];
        #pragma unroll
        for (int mt = 0; mt < MT_; mt++)
          acc[hh][mt] = __builtin_amdgcn_mfma_f32_16x16x32_bf16(A[kk][mt], bv, acc[hh][mt], 0, 0, 0);
      }
  };

  const int NITER = H_/BK;   // 32 (even)
  loadB(0, R0); sE = sp[0];
  loadB(1, R1); sO = sp[0];
  loadA(0, A0);
  storeB(R0, sE, 0);
  sync_lds();

  for (int i = 0; i < NITER; i += 2){
    if (i+2 < NITER){ loadB(i+2, R0); sE = sp[(i+2) >> 1]; }
    loadA(i+1, A1);
    mfma(0, A0);
    storeB(R1, sO, 1);
    sync_lds();
    if (i+3 < NITER){ loadB(i+3, R1); sO = sp[(i+3) >> 1]; }
    if (i+2 < NITER) loadA(i+2, A0);
    mfma(1, A1);
    if (i+2 < NITER){ storeB(R0, sE, 0); sync_lds(); }
  }

  // epilogue: act = silu(gate)*up  (C layout: col=l16, row=quad*4+r)
  #pragma unroll
  for (int mt = 0; mt < MT_; mt++){
    #pragma unroll
    for (int r = 0; r < 4; r++){
      const int m = wave*(TM/4) + mt*16 + quad*4 + r;
      if (m < rows){
        const float g = acc[0][mt][r];
        const float u = acc[1][mt][r];
        const float sg = g / (1.f + __expf(-g));
        act[(size_t)(off + m0 + m)*I_ + (nb + l16)] = f2bf(sg * u);
      }
    }
  }
}

// ---------------------------------------------------------------------------
// GEMM2: buf[slot,h] = act @ W2^T (router weight applied in combine).
// grid: (H/TN=128, 6, E=8), block 256.
// ---------------------------------------------------------------------------
__global__ __launch_bounds__(256, 4)
void gemm2_kernel(const unsigned short* __restrict__ act, const float* __restrict__ w2,
                  const float* __restrict__ s2, const int* __restrict__ offs,
                  float* __restrict__ buf)
{
  const int e   = blockIdx.z;
  const int off = offs[e];
  const int cnt = offs[e+1] - off;
  const int m0  = blockIdx.y * TM;
  if (m0 >= cnt) return;
  const int rows = min(TM, cnt - m0);
  const int nb   = blockIdx.x * TN;

  __shared__ __align__(16) unsigned short Bs[2][TN][LDSB];   // 4608 B

  const int tid  = threadIdx.x;
  const int wave = tid >> 6;
  const int lane = tid & 63;
  const int quad = lane >> 4;
  const int l16  = lane & 15;

  const float* w2e = w2 + (size_t)e * H_ * I_;
  const float* s2e = s2 + (size_t)e * (H_/128) * (I_/128);

  // B staging map: row = tid>>4 (0..15), 4 floats/thread
  const int brow = tid >> 4;
  const int bf4  = tid & 15;              // cols bf4*4 .. +3
  const float* bp = w2e + (size_t)(nb + brow) * I_ + bf4*4;
  const float* sp = s2e + (nb >> 7) * (I_/128);

  const unsigned short* aP[MT_];
  #pragma unroll
  for (int mt = 0; mt < MT_; mt++){
    int sl = off + m0 + wave*(TM/4) + mt*16 + l16;
    sl = min(sl, NPAIR - 1);
    aP[mt] = act + (size_t)sl * I_ + quad*8;
  }

  f32x4 acc[MT_];
  #pragma unroll
  for (int mt = 0; mt < MT_; mt++)
    acc[mt] = (f32x4){0.f, 0.f, 0.f, 0.f};

  float4 R0, R1;
  bf16x8 A0[2][MT_], A1[2][MT_];
  float  sE, sO;

  auto loadB = [&](int t, float4& R){
    R = *(const float4*)(bp + t*BK);
  };
  auto loadA = [&](int t, bf16x8 (*A)[MT_]){
    #pragma unroll
    for (int kk = 0; kk < 2; kk++)
      #pragma unroll
      for (int mt = 0; mt < MT_; mt++)
        A[kk][mt] = *(const bf16x8*)(aP[mt] + t*BK + kk*32);
  };
  auto storeB = [&](const float4& R, float s, int b){
    u16x4 w;
    cvt4((unsigned short*)&w, R, s);
    *(u16x4*)&Bs[b][brow][bf4*4] = w;
  };
  auto mfma = [&](int b, bf16x8 (*A)[MT_]){
    #pragma unroll
    for (int kk = 0; kk < 2; kk++){
      bf16x8 bv = *(const bf16x8*)&Bs[b][l16][kk*32 + quad*8];
      #pragma unroll
      for (int mt = 0; mt < MT_; mt++)
        acc[mt] = __builtin_amdgcn_mfma_f32_16x16x32_bf16(A[kk][mt], bv, acc[mt], 0, 0, 0);
    }
  };

  const int NITER = I_/BK;   // 44 (even)
  loadB(0, R0); sE = sp[0];
  loadB(1, R1); sO = sp[0];
  loadA(0, A0);
  storeB(R0, sE, 0);
  sync_lds();

  for (int i = 0; i < NITER; i += 2){
    if (i+2 < NITER){ loadB(i+2, R0); sE = sp[(i+2) >> 1]; }
    loadA(i+1, A1);
    mfma(0, A0);
    storeB(R1, sO, 1);
    sync_lds();
    if (i+3 < NITER){ loadB(i+3, R1); sO = sp[(i+3) >> 1]; }
    if (i+2 < NITER) loadA(i+2, A0);
    mfma(1, A1);
    if (i+2 < NITER){ storeB(R0, sE, 0); sync_lds(); }
  }

  // epilogue
  #pragma unroll
  for (int mt = 0; mt < MT_; mt++){
    #pragma unroll
    for (int r = 0; r < 4; r++){
      const int m = wave*(TM/4) + mt*16 + quad*4 + r;
      if (m < rows)
        buf[(size_t)(off + m0 + m)*H_ + (nb + l16)] = acc[mt][r];
    }
  }
}

// ---------------------------------------------------------------------------
// Combine: out[t,:] = tw[2t]*buf[sop[2t],:] + tw[2t+1]*buf[sop[2t+1],:]
// ---------------------------------------------------------------------------
__global__ void combine_kernel(const float* __restrict__ buf, const int* __restrict__ sop,
                               const float* __restrict__ tw, float* __restrict__ out){
  const int gid = blockIdx.x*256 + threadIdx.x;
  const int t = gid >> 9;
  const int c = gid & 511;
  const int s0 = sop[2*t], s1 = sop[2*t+1];
  const float w0 = tw[2*t], w1 = tw[2*t+1];
  const float4 v0 = ((const float4*)buf)[(size_t)s0*(H_/4) + c];
  const float4 v1 = ((const float4*)buf)[(size_t)s1*(H_/4) + c];
  float4 o;
  o.x = w0*v0.x + w1*v1.x;
  o.y = w0*v0.y + w1*v1.y;
  o.z = w0*v0.z + w1*v1.z;
  o.w = w0*v0.w + w1*v1.w;
  ((float4*)out)[gid] = o;
}

// ---------------------------------------------------------------------------
extern "C" void kernel_launch(void* const* d_in, const int* in_sizes, int n_in,
                              void* d_out, int out_size, void* d_ws, size_t ws_size,
                              hipStream_t stream){
  const float* x   = (const float*)d_in[0];
  const int*   ids = (const int*)  d_in[1];
  const float* tw  = (const float*)d_in[2];
  const float* w13 = (const float*)d_in[3];
  const float* s13 = (const float*)d_in[4];
  const float* w2  = (const float*)d_in[5];
  const float* s2  = (const float*)d_in[6];
  float* out = (float*)d_out;

  char* ws = (char*)d_ws;
  int* offs = (int*)ws;                                   // 9 ints
  int* ptok = (int*)(ws + 64);                            // 1024 ints
  int* sop  = (int*)(ws + 64 + 4096);                     // 1024 ints
  unsigned short* xg  = (unsigned short*)(ws + 16384);    // [1024][H] bf16 (aliased by buf)
  float*          buf = (float*)(ws + 16384);             // [1024][H] f32
  unsigned short* act = (unsigned short*)(ws + 16384 + (size_t)NPAIR*H_*4);  // [1024][I] bf16

  route_kernel  <<<1, NPAIR, 0, stream>>>(ids, offs, ptok, sop);
  prep_kernel   <<<NPAIR, 256, 0, stream>>>(x, ptok, xg);
  gemm1_kernel  <<<dim3(I_/TN, (NPAIR + TM - 1)/TM, E_), 256, 0, stream>>>(xg, w13, s13, offs, act);
  gemm2_kernel  <<<dim3(H_/TN, (NPAIR + TM - 1)/TM, E_), 256, 0, stream>>>(act, w2, s2, offs, buf);
  combine_kernel<<<(T_*H_/4)/256, 256, 0, stream>>>(buf, sop, tw, out);
}